// Round 12
// baseline (90.645 us; speedup 1.0000x reference)
//
#include <hip/hip_runtime.h>
#include <float.h>
#include <stdint.h>

// CorrLoss via bf16 MFMA, symmetric 128x128 tiles, 3 dispatches.
//   Round 12: 32x32x16 MFMA shape (half the MFMA instrs, -33% LDS reads per
//   FLOP). 256-thr blocks, 4 waves, each wave a 64x64 quadrant = 2x2 frags of
//   32x32 (acc 16 f32/lane). BK=64 single-buffer, XOR-swizzled staging
//   (phys chunk = logical ^ (row&7); row&7==lane&7 for all frags -> shared
//   swizzled offset). Exactly-once partial writes, no value atomics.
//   k0: cast fp32->bf16 (RNE); zero fold counter.
//   k2: 16-block fold -> done-counter last block -> out[0].

#define N_ROWS 4096
#define D_K    512
#define BT     128
#define BK     64
#define NKIT   (D_K / BK)              // 8
#define NTB    (N_ROWS / BT)           // 32
#define NTILES (NTB * (NTB + 1) / 2)   // 528
#define MARGIN 40.0f
#define FOLD_BLOCKS 16

typedef __bf16 bf16_t;
typedef bf16_t bf16x8 __attribute__((ext_vector_type(8)));
typedef float  floatx16 __attribute__((ext_vector_type(16)));
typedef unsigned short ushort_t;
typedef ushort_t ushortx8 __attribute__((ext_vector_type(8)));

#define GLOAD_LDS16(g, l)                                        \
    __builtin_amdgcn_global_load_lds(                            \
        (const __attribute__((address_space(1))) void*)(g),      \
        (__attribute__((address_space(3))) void*)(l), 16, 0, 0)

__device__ __forceinline__ ushort_t f2bf_rne(float x) {
    uint32_t u = __builtin_bit_cast(uint32_t, x);
    return (ushort_t)((u + 0x7FFFu + ((u >> 16) & 1u)) >> 16);
}

__global__ __launch_bounds__(256) void cast_kernel(
    const float* __restrict__ f, ushort_t* __restrict__ o,
    int* __restrict__ counter)
{
    const int gid = blockIdx.x * 256 + threadIdx.x;
    if (gid == 0) *counter = 0;

    const int i = gid * 8;
    const float4 v0 = *(const float4*)(f + i);
    const float4 v1 = *(const float4*)(f + i + 4);
    ushortx8 r;
    r[0] = f2bf_rne(v0.x); r[1] = f2bf_rne(v0.y);
    r[2] = f2bf_rne(v0.z); r[3] = f2bf_rne(v0.w);
    r[4] = f2bf_rne(v1.x); r[5] = f2bf_rne(v1.y);
    r[6] = f2bf_rne(v1.z); r[7] = f2bf_rne(v1.w);
    *(ushortx8*)(o + i) = r;
}

__global__ __launch_bounds__(256, 4) void gram_mfma_kernel(
    const ushort_t* __restrict__ fb, const int* __restrict__ tgt,
    float* __restrict__ ap_part, float* __restrict__ an_part)
{
    // [row][k] row-major, row stride 64 bf16 = 128 B; 16 B k-chunks
    // XOR-swizzled: physical chunk p holds logical chunk p ^ (row & 7).
    __shared__ __align__(16) ushort_t As[BT * BK];   // 16 KB
    __shared__ __align__(16) ushort_t Bs[BT * BK];   // 16 KB
    __shared__ int tgI[BT];
    __shared__ int tgJ[BT];

    // epilogue reductions alias As (dead after the K-loop's final barrier)
    float* apRed  = (float*)As;          // [2][BT]
    float* anRed  = apRed  + 2 * BT;     // [2][BT]
    float* apRedT = anRed  + 2 * BT;     // [2][BT]
    float* anRedT = apRedT + 2 * BT;     // [2][BT]   total 4 KB

    // flat block id -> upper-tri (bi, bj), row-major
    int bi = 0, rem = blockIdx.x;
    while (rem >= NTB - bi) { rem -= NTB - bi; ++bi; }
    const int bj = bi + rem;

    const int tid  = threadIdx.x;
    const int i0   = bi * BT;
    const int j0   = bj * BT;
    const int lane = tid & 63;
    const int wave = tid >> 6;
    const int wr   = wave >> 1;      // row half (0/1): 64 rows
    const int wc   = wave & 1;       // col half (0/1): 64 cols
    const int cl   = lane & 31;      // frag row/col within 32
    const int hh   = lane >> 5;      // k-half (A/B) / row-offset quad (C/D)

    if (tid < BT)            tgI[tid]      = tgt[i0 + tid];
    else if (tid < 2 * BT)   tgJ[tid - BT] = tgt[j0 + tid - BT];

    // staging: pass p, thread t -> flat chunk c = p*256+t; row = c>>3,
    // physical chunk t&7 holds logical (t&7)^(row&7); dest = c*16 (wave-
    // contiguous per pass). 4 passes each for A and B per k-iter.
    const int sr = tid >> 3;                    // 0..31 (+32*p)
    const int sc = (tid & 7) ^ (sr & 7);
    const size_t gA0 = (size_t)(i0 + sr) * D_K + sc * 8;
    const size_t gB0 = (size_t)(j0 + sr) * D_K + sc * 8;
    char* AsB = (char*)As;
    char* BsB = (char*)Bs;

    floatx16 acc[2][2];
#pragma unroll
    for (int a = 0; a < 2; ++a)
#pragma unroll
        for (int b = 0; b < 2; ++b) acc[a][b] = (floatx16)0.0f;

    for (int k0 = 0; k0 < D_K; k0 += BK) {
#pragma unroll
        for (int p = 0; p < 4; ++p) {
            GLOAD_LDS16(fb + gA0 + (size_t)p * 32 * D_K + k0,
                        AsB + p * 4096 + tid * 16);
            GLOAD_LDS16(fb + gB0 + (size_t)p * 32 * D_K + k0,
                        BsB + p * 4096 + tid * 16);
        }
        __syncthreads();

#pragma unroll
        for (int s = 0; s < 4; ++s) {
            // logical chunk = 2s + hh; row&7 == cl&7 for every frag row
            const int pc8 = ((2 * s + hh) ^ (cl & 7)) * 8;
            bf16x8 a0 = *(const bf16x8*)(As + (wr * 64 + cl) * BK + pc8);
            bf16x8 a1 = *(const bf16x8*)(As + (wr * 64 + 32 + cl) * BK + pc8);
            bf16x8 b0 = *(const bf16x8*)(Bs + (wc * 64 + cl) * BK + pc8);
            bf16x8 b1 = *(const bf16x8*)(Bs + (wc * 64 + 32 + cl) * BK + pc8);
            acc[0][0] = __builtin_amdgcn_mfma_f32_32x32x16_bf16(a0, b0, acc[0][0], 0, 0, 0);
            acc[0][1] = __builtin_amdgcn_mfma_f32_32x32x16_bf16(a0, b1, acc[0][1], 0, 0, 0);
            acc[1][0] = __builtin_amdgcn_mfma_f32_32x32x16_bf16(a1, b0, acc[1][0], 0, 0, 0);
            acc[1][1] = __builtin_amdgcn_mfma_f32_32x32x16_bf16(a1, b1, acc[1][1], 0, 0, 0);
        }
        __syncthreads();
    }

    // ---- epilogue: 32x32 C/D layout: col = lane&31,
    //      row = (reg&3) + 8*(reg>>2) + 4*(lane>>5) ----
    const int tj0 = tgJ[wc * 64 + cl];
    const int tj1 = tgJ[wc * 64 + 32 + cl];

    float apT[2], anT[2];
#pragma unroll
    for (int cg = 0; cg < 2; ++cg) { apT[cg] = FLT_MAX; anT[cg] = -FLT_MAX; }

#pragma unroll
    for (int rg = 0; rg < 2; ++rg) {
        const int rbase = wr * 64 + rg * 32 + 4 * hh;
#pragma unroll
        for (int reg = 0; reg < 16; ++reg) {
            const int row = rbase + (reg & 3) + 8 * (reg >> 2);
            const int ti = tgI[row];
            const float v0 = acc[rg][0][reg];
            const float v1 = acc[rg][1][reg];
            float vap = FLT_MAX, van = -FLT_MAX;
            if (ti == tj0) { vap = fminf(vap, v0); apT[0] = fminf(apT[0], v0); }
            else           { van = fmaxf(van, v0); anT[0] = fmaxf(anT[0], v0); }
            if (ti == tj1) { vap = fminf(vap, v1); apT[1] = fminf(apT[1], v1); }
            else           { van = fmaxf(van, v1); anT[1] = fmaxf(anT[1], v1); }
            // direct: fold 32 cols per h-half (masks < 32 preserve hh),
            // v0/v1 already folded -> covers the wave's 64 cols
#pragma unroll
            for (int m = 1; m < 32; m <<= 1) {
                vap = fminf(vap, __shfl_xor(vap, m));
                van = fmaxf(van, __shfl_xor(van, m));
            }
            if (cl == 0) {   // lanes 0 (h=0) and 32 (h=1): distinct rows
                apRed[wc * BT + row] = vap;
                anRed[wc * BT + row] = van;
            }
        }
    }
    // transposed: regs/rg folded in-lane; merge the two h-halves (same col)
#pragma unroll
    for (int cg = 0; cg < 2; ++cg) {
        float vap = apT[cg], van = anT[cg];
        vap = fminf(vap, __shfl_xor(vap, 32));
        van = fmaxf(van, __shfl_xor(van, 32));
        if (lane < 32) {
            apRedT[wr * BT + wc * 64 + cg * 32 + cl] = vap;
            anRedT[wr * BT + wc * 64 + cg * 32 + cl] = van;
        }
    }
    __syncthreads();

    if (tid < BT) {
        ap_part[(size_t)bj * N_ROWS + i0 + tid] =
            fminf(apRed[0 * BT + tid], apRed[1 * BT + tid]);
        an_part[(size_t)bj * N_ROWS + i0 + tid] =
            fmaxf(anRed[0 * BT + tid], anRed[1 * BT + tid]);
        if (bi != bj) {
            ap_part[(size_t)bi * N_ROWS + j0 + tid] =
                fminf(apRedT[0 * BT + tid], apRedT[1 * BT + tid]);
            an_part[(size_t)bi * N_ROWS + j0 + tid] =
                fmaxf(anRedT[0 * BT + tid], anRedT[1 * BT + tid]);
        }
    }
}

__global__ __launch_bounds__(256) void fold_kernel(
    const float* __restrict__ ap_part, const float* __restrict__ an_part,
    float* __restrict__ blk_sum, int* __restrict__ counter,
    float* __restrict__ out)
{
    __shared__ float sred[4];
    const int tid = threadIdx.x;
    const int row = blockIdx.x * 256 + tid;
    const int lane = tid & 63;
    const int wave = tid >> 6;

    float ap = FLT_MAX, an = -FLT_MAX;
#pragma unroll 8
    for (int s = 0; s < NTB; ++s) {
        ap = fminf(ap, ap_part[(size_t)s * N_ROWS + row]);
        an = fmaxf(an, an_part[(size_t)s * N_ROWS + row]);
    }
    const float v = an - ap + MARGIN;
    float local = (v > 0.0f) ? v : 0.0f;
#pragma unroll
    for (int m = 32; m >= 1; m >>= 1) local += __shfl_down(local, m);
    if (lane == 0) sred[wave] = local;
    __syncthreads();

    if (tid == 0) {
        blk_sum[blockIdx.x] = sred[0] + sred[1] + sred[2] + sred[3];
        __threadfence();
        if (atomicAdd(counter, 1) == FOLD_BLOCKS - 1) {
            __threadfence();
            float s = 0.0f;
#pragma unroll
            for (int b = 0; b < FOLD_BLOCKS; ++b) s += blk_sum[b];
            out[0] = s * (1.0f / N_ROWS);
        }
    }
}

extern "C" void kernel_launch(void* const* d_in, const int* in_sizes, int n_in,
                              void* d_out, int out_size, void* d_ws, size_t ws_size,
                              hipStream_t stream)
{
    const float* feat = (const float*)d_in[0];
    const int*   tgt  = (const int*)d_in[1];

    ushort_t* fb      = (ushort_t*)d_ws;                        // 4 MB bf16 feat
    float*    ap_part = (float*)(fb + (size_t)N_ROWS * D_K);    // 512 KB
    float*    an_part = ap_part + (size_t)NTB * N_ROWS;         // 512 KB
    float*    blk_sum = an_part + (size_t)NTB * N_ROWS;         // 64 B
    int*      counter = (int*)(blk_sum + FOLD_BLOCKS);

    cast_kernel<<<(N_ROWS * D_K) / (256 * 8), 256, 0, stream>>>(feat, fb, counter);
    gram_mfma_kernel<<<NTILES, 256, 0, stream>>>(fb, tgt, ap_part, an_part);
    fold_kernel<<<FOLD_BLOCKS, 256, 0, stream>>>(ap_part, an_part, blk_sum,
                                                 counter, (float*)d_out);
}